// Round 4
// baseline (201.542 us; speedup 1.0000x reference)
//
#include <hip/hip_runtime.h>

#define NCLS 36
#define KSEL 50
#define BATCH 8
#define DIM 32
#define NPIX 65536          // 256*256
#define TEMP_ 0.1f
#define BASE_TEMP_ 0.07f
#define ROWS (NCLS*KSEL)    // 1800
#define CHUNKS_PER_B 8      // ceil(1800/256)

// ---------------------------------------------------------------------------
// Kernel A (fused):
//   blocks [0,256):   seg scatter-reduce, one block per (b,d) plane
//   blocks [256,264): per-b class histogram (counts) + zero loss accumulators
//   blocks [264,552): first-K index selection, one wave per (b,c)
// LDS accumulate uses shared-memory atomicAdd: hipcc emits no-return
// ds_add_f32/ds_add_u32 (fire-and-forget, no lgkmcnt stall per update).
// ---------------------------------------------------------------------------
__global__ __launch_bounds__(256) void kA(const float* __restrict__ emb,
                                          const int* __restrict__ lab,
                                          float* __restrict__ seg_sum,
                                          int* __restrict__ counts,
                                          int* __restrict__ order,
                                          float* __restrict__ loss_num)
{
    // stride 37: bank = (37*t + c) % 32 = (5t + c) % 32; random c -> ~2-way (free)
    __shared__ float smem[256 * 37 + 4 * 36];   // + partial-reduce area (38.5 KB)
    float* __restrict__ red = smem + 256 * 37;
    const int bid = blockIdx.x;
    const int tid = threadIdx.x;

    if (bid < 256) {
        // ---- seg role: plane (b, d) ----
        const int b = bid >> 5, d = bid & 31;
        const float4* __restrict__ src  = (const float4*)(emb + (size_t)(b * DIM + d) * NPIX);
        const int4*   __restrict__ lsrc = (const int4*)(lab + (size_t)b * NPIX);
        float* acc = smem + tid * 37;
        #pragma unroll
        for (int c = 0; c < 37; ++c) acc[c] = 0.f;
        for (int i = 0; i < NPIX / 1024; ++i) {   // 64 iters, 4 px/thread/iter
            const int idx = i * 256 + tid;
            float4 v = src[idx];
            int4   l = lsrc[idx];
            // no-return ds_add_f32 into this thread's private row
            atomicAdd(&acc[l.x], v.x);
            atomicAdd(&acc[l.y], v.y);
            atomicAdd(&acc[l.z], v.z);
            atomicAdd(&acc[l.w], v.w);
        }
        __syncthreads();
        // parallel column reduce: 144 threads sum 64 rows each, then 4-way combine
        if (tid < 144) {
            const int c = tid % NCLS, q = tid / NCLS;
            float s = 0.f;
            #pragma unroll
            for (int t = 0; t < 64; ++t) s += smem[(q * 64 + t) * 37 + c];
            red[q * NCLS + c] = s;
        }
        __syncthreads();
        if (tid < NCLS) {
            const float s = red[tid] + red[NCLS + tid] + red[2 * NCLS + tid] + red[3 * NCLS + tid];
            seg_sum[((size_t)b * NCLS + tid) * DIM + d] = s;
        }
    } else if (bid < 264) {
        // ---- counts role: batch b ----
        const int b = bid - 256;
        int* iacc = (int*)smem + tid * 37;
        #pragma unroll
        for (int c = 0; c < 37; ++c) iacc[c] = 0;
        const int4* __restrict__ lsrc = (const int4*)(lab + (size_t)b * NPIX);
        for (int i = 0; i < NPIX / 1024; ++i) {
            int4 l = lsrc[i * 256 + tid];
            atomicAdd(&iacc[l.x], 1);   // no-return ds_add_u32
            atomicAdd(&iacc[l.y], 1);
            atomicAdd(&iacc[l.z], 1);
            atomicAdd(&iacc[l.w], 1);
        }
        __syncthreads();
        if (tid < 144) {
            const int c = tid % NCLS, q = tid / NCLS;
            int s = 0;
            #pragma unroll
            for (int t = 0; t < 64; ++t) s += ((int*)smem)[(q * 64 + t) * 37 + c];
            ((int*)red)[q * NCLS + c] = s;
        }
        __syncthreads();
        if (tid < NCLS) {
            const int* ired = (const int*)red;
            counts[b * NCLS + tid] = ired[tid] + ired[NCLS + tid] + ired[2 * NCLS + tid] + ired[3 * NCLS + tid];
        }
        if (b == 0 && tid < BATCH) loss_num[tid] = 0.f;  // zero accumulators (ws is poisoned)
    } else {
        // ---- topk role: one wave per (b,c), ordered ballot compaction ----
        const int idx = bid - 264;
        const int b = idx / NCLS, c = idx % NCLS;
        if (tid < 64) {
            const int* __restrict__ lb = lab + (size_t)b * NPIX;
            int* __restrict__ dst = order + ((size_t)b * NCLS + c) * KSEL;
            int found = 0;
            int nxt = lb[tid];                        // software prefetch
            for (int n0 = 0; n0 < NPIX && found < KSEL; n0 += 64) {
                const int cur = nxt;
                if (n0 + 64 < NPIX) nxt = lb[n0 + 64 + tid];
                const int match = (cur == c);
                const unsigned long long m = __ballot(match);
                if (match) {
                    const int r = found + __popcll(m & ((1ull << tid) - 1ull));
                    if (r < KSEL) dst[r] = n0 + tid;
                }
                found += __popcll(m);
            }
        }
    }
}

// ---------------------------------------------------------------------------
// Kernel B: per-row contrastive CE. One thread per row p = c_row*K + k.
// 256-thread blocks (4 waves) for latency hiding of the gather.
// ---------------------------------------------------------------------------
__global__ __launch_bounds__(256) void kB(const float* __restrict__ emb,
                                          const int* __restrict__ counts_g,
                                          const int* __restrict__ order_g,
                                          const float* __restrict__ seg_sum,
                                          float* __restrict__ loss_num)
{
    __shared__ float seg[NCLS * DIM];   // normalized per-class means (4.6 KB)
    __shared__ int   cnt[NCLS];
    const int b = blockIdx.x / CHUNKS_PER_B;
    const int chunk = blockIdx.x % CHUNKS_PER_B;
    const int tid = threadIdx.x;

    if (tid < NCLS) cnt[tid] = counts_g[b * NCLS + tid];
    __syncthreads();
    for (int i = tid; i < NCLS * DIM; i += 256) {
        const float cn = (float)max(cnt[i >> 5], 1);
        seg[i] = seg_sum[(size_t)b * NCLS * DIM + i] / cn;
    }
    __syncthreads();

    const int p = chunk * 256 + tid;
    float loss = 0.f;
    if (p < ROWS) {
        const int crow = p / KSEL;
        const int k = p - crow * KSEL;
        if (k < cnt[crow]) {                       // pix_valid; else contributes 0
            const int n = order_g[((size_t)b * NCLS + crow) * KSEL + k];
            float f[DIM];
            const float* __restrict__ eb = emb + (size_t)b * DIM * NPIX + n;
            #pragma unroll
            for (int d = 0; d < DIM; ++d) f[d] = eb[(size_t)d * NPIX];

            // online softmax over valid classes (count>0); track own-class logit
            float m = -1e30f, s = 0.f, lrow = 0.f;
            for (int c = 0; c < NCLS; ++c) {
                if (cnt[c] > 0) {                  // block-uniform branch
                    float acc = 0.f;
                    const float4* sp = (const float4*)(seg + c * DIM);
                    #pragma unroll
                    for (int q = 0; q < 8; ++q) {
                        float4 sv = sp[q];
                        acc += f[q*4+0]*sv.x + f[q*4+1]*sv.y
                             + f[q*4+2]*sv.z + f[q*4+3]*sv.w;
                    }
                    const float l = acc * (1.0f / TEMP_);
                    if (c == crow) lrow = l;
                    const float nm = fmaxf(m, l);
                    s = s * expf(m - nm) + expf(l - nm);
                    m = nm;
                }
            }
            loss = -(TEMP_ / BASE_TEMP_) * (lrow - m - logf(s));
        }
    }
    // per-wave reduction, one atomic per wave
    #pragma unroll
    for (int o = 32; o > 0; o >>= 1) loss += __shfl_down(loss, o);
    if ((tid & 63) == 0) atomicAdd(&loss_num[b], loss);
}

// ---------------------------------------------------------------------------
// Kernel C: finalize on ONE WAVE (64 threads — R1/R2 bug: was launched <<<1,1>>>
// while written for 64 lanes; shfl from unlaunched lanes gave deterministic
// garbage, absmax 21.19 both rounds).
// den[b] = sum_c min(count, K); out = mean_b num/den.
// ---------------------------------------------------------------------------
__global__ __launch_bounds__(64) void kC(const float* __restrict__ loss_num,
                                         const int* __restrict__ counts,
                                         float* __restrict__ out)
{
    const int lane = threadIdx.x;
    int v[BATCH];
    #pragma unroll
    for (int b = 0; b < BATCH; ++b)
        v[b] = (lane < NCLS) ? min(counts[b * NCLS + lane], KSEL) : 0;
    const float num = (lane < BATCH) ? loss_num[lane] : 0.f;

    float total = 0.f;
    #pragma unroll
    for (int b = 0; b < BATCH; ++b) {
        int d = v[b];
        #pragma unroll
        for (int o = 32; o > 0; o >>= 1) d += __shfl_down(d, o);
        d = __shfl(d, 0);
        const float nb = __shfl(num, b);
        if (lane == 0) total += nb / (float)max(d, 1);
    }
    if (lane == 0) out[0] = total * (1.0f / BATCH);
}

extern "C" void kernel_launch(void* const* d_in, const int* in_sizes, int n_in,
                              void* d_out, int out_size, void* d_ws, size_t ws_size,
                              hipStream_t stream)
{
    const float* emb = (const float*)d_in[0];
    const int*   lab = (const int*)d_in[1];

    float* seg_sum  = (float*)d_ws;                         // B*C*D   = 9216 f
    int*   counts   = (int*)(seg_sum + BATCH * NCLS * DIM); // B*C     = 288 i
    int*   order    = counts + BATCH * NCLS;                // B*C*K   = 14400 i
    float* loss_num = (float*)(order + BATCH * NCLS * KSEL);// B       = 8 f
    float* out      = (float*)d_out;

    kA<<<552, 256, 0, stream>>>(emb, lab, seg_sum, counts, order, loss_num);
    kB<<<BATCH * CHUNKS_PER_B, 256, 0, stream>>>(emb, counts, order, seg_sum, loss_num);
    kC<<<1, 64, 0, stream>>>(loss_num, counts, out);   // 64 threads — matches wave-wide shfl
}

// Round 6
// 201.274 us; speedup vs baseline: 1.0013x; 1.0013x over previous
//
#include <hip/hip_runtime.h>

#define NCLS 36
#define KSEL 50
#define BATCH 8
#define DIM 32
#define NPIX 65536          // 256*256
#define TEMP_ 0.1f
#define BASE_TEMP_ 0.07f
#define ROWS (NCLS*KSEL)    // 1800
#define CHUNKS_PER_B 8      // ceil(1800/256)

// ---------------------------------------------------------------------------
// Kernel A (fused):
//   blocks [0,256):   seg scatter-reduce, one block per (b,d) plane
//   blocks [256,264): per-b class histogram (counts) + zero loss accumulators
//   blocks [264,552): first-K index selection, one wave per (b,c)
//
// R3 lesson (rocprof): safe atomicAdd(float*) on LDS = CAS loop -> kA 100us
// at 0.9% VALUBusy / 5% HBM. unsafeAtomicAdd = native no-return ds_add_f32
// (fire-and-forget). Rows are thread-private, so ordering is deterministic;
// R1/R2's identical-absmax failure was the kC launch config, not this.
// ---------------------------------------------------------------------------
__global__ __launch_bounds__(256) void kA(const float* __restrict__ emb,
                                          const int* __restrict__ lab,
                                          float* __restrict__ seg_sum,
                                          int* __restrict__ counts,
                                          int* __restrict__ order,
                                          float* __restrict__ loss_num)
{
    // stride 37: bank = (37*t + c) % 32 = (5t + c) % 32; random c -> ~2-way (free)
    __shared__ float smem[256 * 37 + 4 * 36];   // + partial-reduce area (38.5 KB)
    float* __restrict__ red = smem + 256 * 37;
    const int bid = blockIdx.x;
    const int tid = threadIdx.x;

    if (bid < 256) {
        // ---- seg role: plane (b, d) ----
        const int b = bid >> 5, d = bid & 31;
        const float4* __restrict__ src  = (const float4*)(emb + (size_t)(b * DIM + d) * NPIX);
        const int4*   __restrict__ lsrc = (const int4*)(lab + (size_t)b * NPIX);
        float* acc = smem + tid * 37;
        #pragma unroll
        for (int c = 0; c < 37; ++c) acc[c] = 0.f;
        for (int i = 0; i < NPIX / 1024; ++i) {   // 64 iters, 4 px/thread/iter
            const int idx = i * 256 + tid;
            float4 v = src[idx];
            int4   l = lsrc[idx];
            // native no-return ds_add_f32 into this thread's private row
            unsafeAtomicAdd(&acc[l.x], v.x);
            unsafeAtomicAdd(&acc[l.y], v.y);
            unsafeAtomicAdd(&acc[l.z], v.z);
            unsafeAtomicAdd(&acc[l.w], v.w);
        }
        __syncthreads();
        // parallel column reduce: 144 threads sum 64 rows each, then 4-way combine
        if (tid < 144) {
            const int c = tid % NCLS, q = tid / NCLS;
            float s = 0.f;
            #pragma unroll
            for (int t = 0; t < 64; ++t) s += smem[(q * 64 + t) * 37 + c];
            red[q * NCLS + c] = s;
        }
        __syncthreads();
        if (tid < NCLS) {
            const float s = red[tid] + red[NCLS + tid] + red[2 * NCLS + tid] + red[3 * NCLS + tid];
            seg_sum[((size_t)b * NCLS + tid) * DIM + d] = s;
        }
    } else if (bid < 264) {
        // ---- counts role: batch b (int atomicAdd is already native ds_add_u32) ----
        const int b = bid - 256;
        int* iacc = (int*)smem + tid * 37;
        #pragma unroll
        for (int c = 0; c < 37; ++c) iacc[c] = 0;
        const int4* __restrict__ lsrc = (const int4*)(lab + (size_t)b * NPIX);
        for (int i = 0; i < NPIX / 1024; ++i) {
            int4 l = lsrc[i * 256 + tid];
            atomicAdd(&iacc[l.x], 1);
            atomicAdd(&iacc[l.y], 1);
            atomicAdd(&iacc[l.z], 1);
            atomicAdd(&iacc[l.w], 1);
        }
        __syncthreads();
        if (tid < 144) {
            const int c = tid % NCLS, q = tid / NCLS;
            int s = 0;
            #pragma unroll
            for (int t = 0; t < 64; ++t) s += ((int*)smem)[(q * 64 + t) * 37 + c];
            ((int*)red)[q * NCLS + c] = s;
        }
        __syncthreads();
        if (tid < NCLS) {
            const int* ired = (const int*)red;
            counts[b * NCLS + tid] = ired[tid] + ired[NCLS + tid] + ired[2 * NCLS + tid] + ired[3 * NCLS + tid];
        }
        if (b == 0 && tid < BATCH) loss_num[tid] = 0.f;  // zero accumulators (ws is poisoned)
    } else {
        // ---- topk role: one wave per (b,c), ordered ballot compaction ----
        const int idx = bid - 264;
        const int b = idx / NCLS, c = idx % NCLS;
        if (tid < 64) {
            const int* __restrict__ lb = lab + (size_t)b * NPIX;
            int* __restrict__ dst = order + ((size_t)b * NCLS + c) * KSEL;
            int found = 0;
            int nxt = lb[tid];                        // software prefetch
            for (int n0 = 0; n0 < NPIX && found < KSEL; n0 += 64) {
                const int cur = nxt;
                if (n0 + 64 < NPIX) nxt = lb[n0 + 64 + tid];
                const int match = (cur == c);
                const unsigned long long m = __ballot(match);
                if (match) {
                    const int r = found + __popcll(m & ((1ull << tid) - 1ull));
                    if (r < KSEL) dst[r] = n0 + tid;
                }
                found += __popcll(m);
            }
        }
    }
}

// ---------------------------------------------------------------------------
// Kernel B: per-row contrastive CE. One thread per row p = c_row*K + k.
// 256-thread blocks (4 waves) for latency hiding of the gather.
// ---------------------------------------------------------------------------
__global__ __launch_bounds__(256) void kB(const float* __restrict__ emb,
                                          const int* __restrict__ counts_g,
                                          const int* __restrict__ order_g,
                                          const float* __restrict__ seg_sum,
                                          float* __restrict__ loss_num)
{
    __shared__ float seg[NCLS * DIM];   // normalized per-class means (4.6 KB)
    __shared__ int   cnt[NCLS];
    const int b = blockIdx.x / CHUNKS_PER_B;
    const int chunk = blockIdx.x % CHUNKS_PER_B;
    const int tid = threadIdx.x;

    if (tid < NCLS) cnt[tid] = counts_g[b * NCLS + tid];
    __syncthreads();
    for (int i = tid; i < NCLS * DIM; i += 256) {
        const float cn = (float)max(cnt[i >> 5], 1);
        seg[i] = seg_sum[(size_t)b * NCLS * DIM + i] / cn;
    }
    __syncthreads();

    const int p = chunk * 256 + tid;
    float loss = 0.f;
    if (p < ROWS) {
        const int crow = p / KSEL;
        const int k = p - crow * KSEL;
        if (k < cnt[crow]) {                       // pix_valid; else contributes 0
            const int n = order_g[((size_t)b * NCLS + crow) * KSEL + k];
            float f[DIM];
            const float* __restrict__ eb = emb + (size_t)b * DIM * NPIX + n;
            #pragma unroll
            for (int d = 0; d < DIM; ++d) f[d] = eb[(size_t)d * NPIX];

            // online softmax over valid classes (count>0); track own-class logit
            float m = -1e30f, s = 0.f, lrow = 0.f;
            for (int c = 0; c < NCLS; ++c) {
                if (cnt[c] > 0) {                  // block-uniform branch
                    float acc = 0.f;
                    const float4* sp = (const float4*)(seg + c * DIM);
                    #pragma unroll
                    for (int q = 0; q < 8; ++q) {
                        float4 sv = sp[q];
                        acc += f[q*4+0]*sv.x + f[q*4+1]*sv.y
                             + f[q*4+2]*sv.z + f[q*4+3]*sv.w;
                    }
                    const float l = acc * (1.0f / TEMP_);
                    if (c == crow) lrow = l;
                    const float nm = fmaxf(m, l);
                    s = s * expf(m - nm) + expf(l - nm);
                    m = nm;
                }
            }
            loss = -(TEMP_ / BASE_TEMP_) * (lrow - m - logf(s));
        }
    }
    // per-wave reduction, one atomic per wave
    #pragma unroll
    for (int o = 32; o > 0; o >>= 1) loss += __shfl_down(loss, o);
    if ((tid & 63) == 0) atomicAdd(&loss_num[b], loss);
}

// ---------------------------------------------------------------------------
// Kernel C: finalize on one wave (launched <<<1,64>>> — wave-wide shfl).
// den[b] = sum_c min(count, K); out = mean_b num/den.
// ---------------------------------------------------------------------------
__global__ __launch_bounds__(64) void kC(const float* __restrict__ loss_num,
                                         const int* __restrict__ counts,
                                         float* __restrict__ out)
{
    const int lane = threadIdx.x;
    int v[BATCH];
    #pragma unroll
    for (int b = 0; b < BATCH; ++b)
        v[b] = (lane < NCLS) ? min(counts[b * NCLS + lane], KSEL) : 0;
    const float num = (lane < BATCH) ? loss_num[lane] : 0.f;

    float total = 0.f;
    #pragma unroll
    for (int b = 0; b < BATCH; ++b) {
        int d = v[b];
        #pragma unroll
        for (int o = 32; o > 0; o >>= 1) d += __shfl_down(d, o);
        d = __shfl(d, 0);
        const float nb = __shfl(num, b);
        if (lane == 0) total += nb / (float)max(d, 1);
    }
    if (lane == 0) out[0] = total * (1.0f / BATCH);
}

extern "C" void kernel_launch(void* const* d_in, const int* in_sizes, int n_in,
                              void* d_out, int out_size, void* d_ws, size_t ws_size,
                              hipStream_t stream)
{
    const float* emb = (const float*)d_in[0];
    const int*   lab = (const int*)d_in[1];

    float* seg_sum  = (float*)d_ws;                         // B*C*D   = 9216 f
    int*   counts   = (int*)(seg_sum + BATCH * NCLS * DIM); // B*C     = 288 i
    int*   order    = counts + BATCH * NCLS;                // B*C*K   = 14400 i
    float* loss_num = (float*)(order + BATCH * NCLS * KSEL);// B       = 8 f
    float* out      = (float*)d_out;

    kA<<<552, 256, 0, stream>>>(emb, lab, seg_sum, counts, order, loss_num);
    kB<<<BATCH * CHUNKS_PER_B, 256, 0, stream>>>(emb, counts, order, seg_sum, loss_num);
    kC<<<1, 64, 0, stream>>>(loss_num, counts, out);
}

// Round 7
// 195.783 us; speedup vs baseline: 1.0294x; 1.0280x over previous
//
#include <hip/hip_runtime.h>

#define NCLS 36
#define KSEL 50
#define BATCH 8
#define DIM 32
#define NPIX 65536          // 256*256
#define TEMP_ 0.1f
#define BASE_TEMP_ 0.07f
#define ROWS (NCLS*KSEL)    // 1800
#define CHUNKS_PER_B 8      // ceil(1800/256) with 256-thread blocks

// LDS atomic helpers: MUST see addrspace(3) + workgroup scope so the compiler
// emits native no-return ds_add_f32 / ds_add_u32.
// R3/R5 lesson: atomicAdd AND unsafeAtomicAdd on a generic float* both took a
// ~900-cy-per-op slow path (kA 100us, 3750 cy/iter = 4 x HBM latency).
#define LDS_FADD(slot, val) \
    __hip_atomic_fetch_add(&(slot), (val), __ATOMIC_RELAXED, __HIP_MEMORY_SCOPE_WORKGROUP)
#define LDS_IADD(slot, val) \
    __hip_atomic_fetch_add(&(slot), (val), __ATOMIC_RELAXED, __HIP_MEMORY_SCOPE_WORKGROUP)

// ---------------------------------------------------------------------------
// Kernel A (fused):
//   blocks [0,256):   seg scatter-reduce, one block per (b,d) plane
//   blocks [256,264): per-b class histogram (counts)
//   blocks [264,552): first-K index selection, one wave per (b,c)
// ---------------------------------------------------------------------------
__global__ __launch_bounds__(256) void kA(const float* __restrict__ emb,
                                          const int* __restrict__ lab,
                                          float* __restrict__ seg_sum,
                                          int* __restrict__ counts,
                                          int* __restrict__ order)
{
    // stride 37: bank = (37*t + c) % 32 = (5t + c) % 32; random c -> ~2-way (free)
    __shared__ float smem[256 * 37 + 4 * 36];   // + partial-reduce area (38.5 KB)
    float* __restrict__ red = smem + 256 * 37;
    const int bid = blockIdx.x;
    const int tid = threadIdx.x;

    if (bid < 256) {
        // ---- seg role: plane (b, d) ----
        const int b = bid >> 5, d = bid & 31;
        const float4* __restrict__ src  = (const float4*)(emb + (size_t)(b * DIM + d) * NPIX);
        const int4*   __restrict__ lsrc = (const int4*)(lab + (size_t)b * NPIX);
        const int row = tid * 37;
        #pragma unroll
        for (int c = 0; c < 37; ++c) smem[row + c] = 0.f;
        // 2-deep software pipeline: load i+1 before accumulating i
        float4 v = src[tid];
        int4   l = lsrc[tid];
        for (int i = 0; i < NPIX / 1024; ++i) {   // 64 iters, 4 px/thread/iter
            const float4 vc = v;
            const int4   lc = l;
            if (i + 1 < NPIX / 1024) {
                const int idx = (i + 1) * 256 + tid;
                v = src[idx];
                l = lsrc[idx];
            }
            LDS_FADD(smem[row + lc.x], vc.x);   // no-return ds_add_f32
            LDS_FADD(smem[row + lc.y], vc.y);
            LDS_FADD(smem[row + lc.z], vc.z);
            LDS_FADD(smem[row + lc.w], vc.w);
        }
        __syncthreads();
        // parallel column reduce: 144 threads sum 64 rows each, then 4-way combine
        if (tid < 144) {
            const int c = tid % NCLS, q = tid / NCLS;
            float s = 0.f;
            #pragma unroll
            for (int t = 0; t < 64; ++t) s += smem[(q * 64 + t) * 37 + c];
            red[q * NCLS + c] = s;
        }
        __syncthreads();
        if (tid < NCLS) {
            const float s = red[tid] + red[NCLS + tid] + red[2 * NCLS + tid] + red[3 * NCLS + tid];
            seg_sum[((size_t)b * NCLS + tid) * DIM + d] = s;
        }
    } else if (bid < 264) {
        // ---- counts role: batch b ----
        const int b = bid - 256;
        int* __restrict__ ismem = (int*)smem;
        const int row = tid * 37;
        #pragma unroll
        for (int c = 0; c < 37; ++c) ismem[row + c] = 0;
        const int4* __restrict__ lsrc = (const int4*)(lab + (size_t)b * NPIX);
        int4 l = lsrc[tid];
        for (int i = 0; i < NPIX / 1024; ++i) {
            const int4 lc = l;
            if (i + 1 < NPIX / 1024) l = lsrc[(i + 1) * 256 + tid];
            LDS_IADD(ismem[row + lc.x], 1);     // no-return ds_add_u32
            LDS_IADD(ismem[row + lc.y], 1);
            LDS_IADD(ismem[row + lc.z], 1);
            LDS_IADD(ismem[row + lc.w], 1);
        }
        __syncthreads();
        if (tid < 144) {
            const int c = tid % NCLS, q = tid / NCLS;
            int s = 0;
            #pragma unroll
            for (int t = 0; t < 64; ++t) s += ismem[(q * 64 + t) * 37 + c];
            ((int*)red)[q * NCLS + c] = s;
        }
        __syncthreads();
        if (tid < NCLS) {
            const int* ired = (const int*)red;
            counts[b * NCLS + tid] = ired[tid] + ired[NCLS + tid] + ired[2 * NCLS + tid] + ired[3 * NCLS + tid];
        }
    } else {
        // ---- topk role: one wave per (b,c), ordered ballot compaction ----
        const int idx = bid - 264;
        const int b = idx / NCLS, c = idx % NCLS;
        if (tid < 64) {
            const int* __restrict__ lb = lab + (size_t)b * NPIX;
            int* __restrict__ dst = order + ((size_t)b * NCLS + c) * KSEL;
            int found = 0;
            int nxt = lb[tid];                        // software prefetch
            for (int n0 = 0; n0 < NPIX && found < KSEL; n0 += 64) {
                const int cur = nxt;
                if (n0 + 64 < NPIX) nxt = lb[n0 + 64 + tid];
                const int match = (cur == c);
                const unsigned long long m = __ballot(match);
                if (match) {
                    const int r = found + __popcll(m & ((1ull << tid) - 1ull));
                    if (r < KSEL) dst[r] = n0 + tid;
                }
                found += __popcll(m);
            }
        }
    }
}

// ---------------------------------------------------------------------------
// Kernel B: per-row contrastive CE. One thread per row p = c_row*K + k.
// 256-thread blocks. NO global atomics: one partial per block into d_ws.
// ---------------------------------------------------------------------------
__global__ __launch_bounds__(256) void kB(const float* __restrict__ emb,
                                          const int* __restrict__ counts_g,
                                          const int* __restrict__ order_g,
                                          const float* __restrict__ seg_sum,
                                          float* __restrict__ part)
{
    __shared__ float seg[NCLS * DIM];   // normalized per-class means (4.6 KB)
    __shared__ int   cnt[NCLS];
    __shared__ float wpart[4];
    const int b = blockIdx.x / CHUNKS_PER_B;
    const int chunk = blockIdx.x % CHUNKS_PER_B;
    const int tid = threadIdx.x;

    if (tid < NCLS) cnt[tid] = counts_g[b * NCLS + tid];
    __syncthreads();
    for (int i = tid; i < NCLS * DIM; i += 256) {
        const float cn = (float)max(cnt[i >> 5], 1);
        seg[i] = seg_sum[(size_t)b * NCLS * DIM + i] / cn;
    }
    __syncthreads();

    const int p = chunk * 256 + tid;
    float loss = 0.f;
    if (p < ROWS) {
        const int crow = p / KSEL;
        const int k = p - crow * KSEL;
        if (k < cnt[crow]) {                       // pix_valid; else contributes 0
            const int n = order_g[((size_t)b * NCLS + crow) * KSEL + k];
            float f[DIM];
            const float* __restrict__ eb = emb + (size_t)b * DIM * NPIX + n;
            #pragma unroll
            for (int d = 0; d < DIM; ++d) f[d] = eb[(size_t)d * NPIX];

            // online softmax over valid classes (count>0); track own-class logit
            float m = -1e30f, s = 0.f, lrow = 0.f;
            for (int c = 0; c < NCLS; ++c) {
                if (cnt[c] > 0) {                  // block-uniform branch
                    float acc = 0.f;
                    const float4* sp = (const float4*)(seg + c * DIM);
                    #pragma unroll
                    for (int q = 0; q < 8; ++q) {
                        float4 sv = sp[q];
                        acc += f[q*4+0]*sv.x + f[q*4+1]*sv.y
                             + f[q*4+2]*sv.z + f[q*4+3]*sv.w;
                    }
                    const float l = acc * (1.0f / TEMP_);
                    if (c == crow) lrow = l;
                    const float nm = fmaxf(m, l);
                    s = s * expf(m - nm) + expf(l - nm);
                    m = nm;
                }
            }
            loss = -(TEMP_ / BASE_TEMP_) * (lrow - m - logf(s));
        }
    }
    // wave reduction, then cross-wave via LDS; one plain store per block
    #pragma unroll
    for (int o = 32; o > 0; o >>= 1) loss += __shfl_down(loss, o);
    if ((tid & 63) == 0) wpart[tid >> 6] = loss;
    __syncthreads();
    if (tid == 0) part[b * CHUNKS_PER_B + chunk] = wpart[0] + wpart[1] + wpart[2] + wpart[3];
}

// ---------------------------------------------------------------------------
// Kernel C: finalize on one wave (launched <<<1,64>>>): sum kB partials,
// den[b] = sum_c min(count, K); out = mean_b num/den. Fully deterministic.
// ---------------------------------------------------------------------------
__global__ __launch_bounds__(64) void kC(const float* __restrict__ part,
                                         const int* __restrict__ counts,
                                         float* __restrict__ out)
{
    const int lane = threadIdx.x;
    float total = 0.f;
    #pragma unroll
    for (int b = 0; b < BATCH; ++b) {
        float pn = (lane < CHUNKS_PER_B) ? part[b * CHUNKS_PER_B + lane] : 0.f;
        #pragma unroll
        for (int o = 32; o > 0; o >>= 1) pn += __shfl_down(pn, o);
        int d = (lane < NCLS) ? min(counts[b * NCLS + lane], KSEL) : 0;
        #pragma unroll
        for (int o = 32; o > 0; o >>= 1) d += __shfl_down(d, o);
        if (lane == 0) total += pn / (float)max(d, 1);
    }
    if (lane == 0) out[0] = total * (1.0f / BATCH);
}

extern "C" void kernel_launch(void* const* d_in, const int* in_sizes, int n_in,
                              void* d_out, int out_size, void* d_ws, size_t ws_size,
                              hipStream_t stream)
{
    const float* emb = (const float*)d_in[0];
    const int*   lab = (const int*)d_in[1];

    float* seg_sum = (float*)d_ws;                          // B*C*D   = 9216 f
    int*   counts  = (int*)(seg_sum + BATCH * NCLS * DIM);  // B*C     = 288 i
    int*   order   = counts + BATCH * NCLS;                 // B*C*K   = 14400 i
    float* part    = (float*)(order + BATCH * NCLS * KSEL); // B*CHUNKS = 64 f
    float* out     = (float*)d_out;

    kA<<<552, 256, 0, stream>>>(emb, lab, seg_sum, counts, order);
    kB<<<BATCH * CHUNKS_PER_B, 256, 0, stream>>>(emb, counts, order, seg_sum, part);
    kC<<<1, 64, 0, stream>>>(part, counts, out);
}